// Round 1
// baseline (2160.273 us; speedup 1.0000x reference)
//
#include <hip/hip_runtime.h>
#include <math.h>

// Problem constants (validated against in_sizes at runtime)
// x: [N,128] f32, edges: [2,E] int32, W0: [128,128], b0: [128], W1: [128,64], b1: [64]

__global__ void init_deg_kernel(float* __restrict__ deg, int n) {
    int i = blockIdx.x * blockDim.x + threadIdx.x;
    if (i < n) deg[i] = 1.0f;  // self-loop
}

__global__ void deg_count_kernel(const int* __restrict__ dst, float* __restrict__ deg, int E) {
    int i = blockIdx.x * blockDim.x + threadIdx.x;
    if (i < E) atomicAdd(&deg[dst[i]], 1.0f);
}

__global__ void dinv_kernel(const float* __restrict__ deg, float* __restrict__ dinv, int n) {
    int i = blockIdx.x * blockDim.x + threadIdx.x;
    if (i < n) {
        float d = deg[i];
        dinv[i] = (d > 0.0f) ? rsqrtf(d) : 0.0f;
    }
}

// h = x @ W, then hs = h * dinv[row]; write hs to BOTH hs (gather source) and
// agg (initializes aggregation with the self-loop contribution).
// K is always 128. OUTC is 128 (layer 1) or 64 (layer 2).
template <int OUTC>
__global__ void gemm_scale_kernel(const float* __restrict__ x, const float* __restrict__ W,
                                  const float* __restrict__ dinv,
                                  float* __restrict__ hs, float* __restrict__ agg, int n) {
    constexpr int TPR  = OUTC / 4;      // threads per row (each thread: 4 cols)
    constexpr int ROWS = 256 / TPR;     // rows per block (8 or 16)
    constexpr int KT   = 32;            // K tile

    __shared__ float Ws[KT][OUTC];
    __shared__ float xs[ROWS][KT];

    const int tid  = threadIdx.x;
    const int r    = tid / TPR;
    const int cg   = tid % TPR;
    const int row0 = blockIdx.x * ROWS;
    const int row  = row0 + r;

    float acc0 = 0.f, acc1 = 0.f, acc2 = 0.f, acc3 = 0.f;

    for (int kt = 0; kt < 128; kt += KT) {
        // stage W tile: KT*OUTC floats, float4 per thread per pass
        constexpr int WLOAD = (KT * OUTC) / (256 * 4);
        #pragma unroll
        for (int l = 0; l < WLOAD; ++l) {
            int idx = (tid + l * 256) * 4;          // linear element index in tile
            int kk  = idx / OUTC;
            int cc  = idx % OUTC;
            *(float4*)&Ws[kk][cc] = *(const float4*)&W[(kt + kk) * OUTC + cc];
        }
        // stage x tile: ROWS*KT floats
        constexpr int XLOAD = ROWS * KT;
        for (int idx = tid; idx < XLOAD; idx += 256) {
            int rr = idx / KT, kk = idx % KT;
            int grow = row0 + rr;
            xs[rr][kk] = (grow < n) ? x[grow * 128 + kt + kk] : 0.0f;
        }
        __syncthreads();
        #pragma unroll
        for (int k = 0; k < KT; ++k) {
            float xv = xs[r][k];
            float4 w = *(const float4*)&Ws[k][cg * 4];
            acc0 += xv * w.x; acc1 += xv * w.y; acc2 += xv * w.z; acc3 += xv * w.w;
        }
        __syncthreads();
    }

    if (row < n) {
        float s = dinv[row];
        float4 v = make_float4(acc0 * s, acc1 * s, acc2 * s, acc3 * s);
        *(float4*)&hs[row * OUTC + cg * 4]  = v;
        *(float4*)&agg[row * OUTC + cg * 4] = v;
    }
}

// agg[dst] += hs[src] over all edges; OUTC/4 threads per edge, float4 gather.
template <int OUTC>
__global__ void scatter_kernel(const int* __restrict__ src, const int* __restrict__ dst,
                               const float* __restrict__ hs, float* __restrict__ agg, int E) {
    constexpr int TPE = OUTC / 4;
    int t = blockIdx.x * blockDim.x + threadIdx.x;
    if (t >= E * TPE) return;
    int e = t / TPE;
    int p = t % TPE;
    int s = src[e];
    int d = dst[e];
    float4 v = *(const float4*)&hs[s * OUTC + p * 4];
    float* a = &agg[d * OUTC + p * 4];
    atomicAdd(a + 0, v.x);
    atomicAdd(a + 1, v.y);
    atomicAdd(a + 2, v.z);
    atomicAdd(a + 3, v.w);
}

// out = agg*dinv[row] + b, optional sigmoid. In-place safe (elementwise).
template <int OUTC, bool SIG>
__global__ void finish_kernel(const float* __restrict__ agg, const float* __restrict__ dinv,
                              const float* __restrict__ bias, float* __restrict__ out, int n) {
    constexpr int TPR = OUTC / 4;
    int t = blockIdx.x * blockDim.x + threadIdx.x;
    if (t >= n * TPR) return;
    int row = t / TPR;
    int c   = (t % TPR) * 4;
    float s = dinv[row];
    float4 v  = *(const float4*)&agg[row * OUTC + c];
    float4 bb = *(const float4*)&bias[c];
    v.x = v.x * s + bb.x;
    v.y = v.y * s + bb.y;
    v.z = v.z * s + bb.z;
    v.w = v.w * s + bb.w;
    if (SIG) {
        v.x = 1.0f / (1.0f + expf(-v.x));
        v.y = 1.0f / (1.0f + expf(-v.y));
        v.z = 1.0f / (1.0f + expf(-v.z));
        v.w = 1.0f / (1.0f + expf(-v.w));
    }
    *(float4*)&out[row * OUTC + c] = v;
}

static inline size_t align256(size_t x) { return (x + 255) & ~size_t(255); }

extern "C" void kernel_launch(void* const* d_in, const int* in_sizes, int n_in,
                              void* d_out, int out_size, void* d_ws, size_t ws_size,
                              hipStream_t stream) {
    const float* x   = (const float*)d_in[0];
    const int*   e32 = (const int*)d_in[1];   // [2,E] int32 (jax demotes int64)
    const float* W0  = (const float*)d_in[2];
    const float* b0  = (const float*)d_in[3];
    const float* W1  = (const float*)d_in[4];
    const float* b1  = (const float*)d_in[5];
    float* out = (float*)d_out;

    const int N = in_sizes[0] / 128;   // 50000
    const int E = in_sizes[1] / 2;     // 800000
    const int* src = e32;
    const int* dst = e32 + E;

    // Workspace layout
    char* p = (char*)d_ws;
    float* deg  = (float*)p; p += align256((size_t)N * 4);
    float* dinv = (float*)p; p += align256((size_t)N * 4);
    float* hs   = (float*)p; p += align256((size_t)N * 128 * 4);   // reused for layer 2 (64 cols)
    float* agg  = (float*)p; p += align256((size_t)N * 128 * 4);   // layer-1 agg, then act (in-place)
    float* agg2 = (float*)p; p += align256((size_t)N * 64 * 4);

    const int B = 256;

    // degrees
    init_deg_kernel<<<(N + B - 1) / B, B, 0, stream>>>(deg, N);
    deg_count_kernel<<<(E + B - 1) / B, B, 0, stream>>>(dst, deg, E);
    dinv_kernel<<<(N + B - 1) / B, B, 0, stream>>>(deg, dinv, N);

    // ---- Layer 1: 128 -> 128, sigmoid ----
    gemm_scale_kernel<128><<<(N + 7) / 8, B, 0, stream>>>(x, W0, dinv, hs, agg, N);
    scatter_kernel<128><<<((size_t)E * 32 + B - 1) / B, B, 0, stream>>>(src, dst, hs, agg, E);
    finish_kernel<128, true><<<((size_t)N * 32 + B - 1) / B, B, 0, stream>>>(agg, dinv, b0, agg, N);

    // ---- Layer 2: 128 -> 64, no activation ----
    gemm_scale_kernel<64><<<(N + 15) / 16, B, 0, stream>>>(agg, W1, dinv, hs, agg2, N);
    scatter_kernel<64><<<((size_t)E * 16 + B - 1) / B, B, 0, stream>>>(src, dst, hs, agg2, E);
    finish_kernel<64, false><<<((size_t)N * 16 + B - 1) / B, B, 0, stream>>>(agg2, dinv, b1, out, N);
}

// Round 2
// 274.187 us; speedup vs baseline: 7.8788x; 7.8788x over previous
//
#include <hip/hip_runtime.h>
#include <math.h>

#define BLK 256

// ---------------- degree / CSR build ----------------

__global__ void deg_count_kernel(const int* __restrict__ dst, int* __restrict__ deg, int E) {
    int i = blockIdx.x * blockDim.x + threadIdx.x;
    if (i < E) atomicAdd(&deg[dst[i]], 1);
}

__global__ void dinv_kernel(const int* __restrict__ deg, float* __restrict__ dinv, int n) {
    int i = blockIdx.x * blockDim.x + threadIdx.x;
    if (i < n) dinv[i] = rsqrtf((float)(deg[i] + 1));  // +1 self-loop
}

// Exclusive scan of deg into rowptr: 1024 elements per block (256 thr x 4).
__global__ void scan1_kernel(const int* __restrict__ deg, int* __restrict__ rowptr,
                             int* __restrict__ bsum, int n) {
    __shared__ int s[BLK];
    int tid = threadIdx.x;
    int base = blockIdx.x * 1024 + tid * 4;
    int v[4];
    int sum = 0;
    #pragma unroll
    for (int j = 0; j < 4; ++j) {
        v[j] = (base + j < n) ? deg[base + j] : 0;
        sum += v[j];
    }
    s[tid] = sum;
    __syncthreads();
    #pragma unroll
    for (int off = 1; off < BLK; off <<= 1) {
        int t = 0;
        if (tid >= off) t = s[tid - off];
        __syncthreads();
        if (tid >= off) s[tid] += t;
        __syncthreads();
    }
    int run = s[tid] - sum;  // exclusive prefix for this thread within block
    #pragma unroll
    for (int j = 0; j < 4; ++j) {
        if (base + j < n) rowptr[base + j] = run;
        run += v[j];
    }
    if (tid == BLK - 1) bsum[blockIdx.x] = s[BLK - 1];
}

// Exclusive scan of block sums (nb <= 256).
__global__ void scan2_kernel(int* __restrict__ bsum, int nb) {
    __shared__ int s[BLK];
    int tid = threadIdx.x;
    int v = (tid < nb) ? bsum[tid] : 0;
    s[tid] = v;
    __syncthreads();
    #pragma unroll
    for (int off = 1; off < BLK; off <<= 1) {
        int t = 0;
        if (tid >= off) t = s[tid - off];
        __syncthreads();
        if (tid >= off) s[tid] += t;
        __syncthreads();
    }
    if (tid < nb) bsum[tid] = s[tid] - v;
}

__global__ void scan3_kernel(int* __restrict__ rowptr, const int* __restrict__ bsum,
                             int n, int E) {
    int i = blockIdx.x * blockDim.x + threadIdx.x;
    if (i < n) rowptr[i] += bsum[i >> 10];
    if (i == 0) rowptr[n] = E;
}

__global__ void cursor_init_kernel(const int* __restrict__ rowptr, int* __restrict__ cursor, int n) {
    int i = blockIdx.x * blockDim.x + threadIdx.x;
    if (i < n) cursor[i] = rowptr[i];
}

__global__ void fill_csr_kernel(const int* __restrict__ src, const int* __restrict__ dst,
                                int* __restrict__ cursor, int* __restrict__ csr_src, int E) {
    int e = blockIdx.x * blockDim.x + threadIdx.x;
    if (e < E) {
        int d = dst[e];
        int pos = atomicAdd(&cursor[d], 1);
        csr_src[pos] = src[e];
    }
}

// ---------------- GEMM: hs = (x @ W) * dinv[row] ----------------

template <int OUTC>
__global__ void gemm_scale_kernel(const float* __restrict__ x, const float* __restrict__ W,
                                  const float* __restrict__ dinv,
                                  float* __restrict__ hs, int n) {
    constexpr int TPR  = OUTC / 4;
    constexpr int ROWS = 256 / TPR;
    constexpr int KT   = 32;

    __shared__ float Ws[KT][OUTC];
    __shared__ float xs[ROWS][KT];

    const int tid  = threadIdx.x;
    const int r    = tid / TPR;
    const int cg   = tid % TPR;
    const int row0 = blockIdx.x * ROWS;
    const int row  = row0 + r;

    float acc0 = 0.f, acc1 = 0.f, acc2 = 0.f, acc3 = 0.f;

    for (int kt = 0; kt < 128; kt += KT) {
        constexpr int WLOAD = (KT * OUTC) / (256 * 4);
        #pragma unroll
        for (int l = 0; l < WLOAD; ++l) {
            int idx = (tid + l * 256) * 4;
            int kk  = idx / OUTC;
            int cc  = idx % OUTC;
            *(float4*)&Ws[kk][cc] = *(const float4*)&W[(kt + kk) * OUTC + cc];
        }
        constexpr int XLOAD = ROWS * KT;
        for (int idx = tid; idx < XLOAD; idx += 256) {
            int rr = idx / KT, kk = idx % KT;
            int grow = row0 + rr;
            xs[rr][kk] = (grow < n) ? x[grow * 128 + kt + kk] : 0.0f;
        }
        __syncthreads();
        #pragma unroll
        for (int k = 0; k < KT; ++k) {
            float xv = xs[r][k];
            float4 w = *(const float4*)&Ws[k][cg * 4];
            acc0 += xv * w.x; acc1 += xv * w.y; acc2 += xv * w.z; acc3 += xv * w.w;
        }
        __syncthreads();
    }

    if (row < n) {
        float s = dinv[row];
        float4 v = make_float4(acc0 * s, acc1 * s, acc2 * s, acc3 * s);
        *(float4*)&hs[row * OUTC + cg * 4] = v;
    }
}

// ---------------- aggregate: out[d] = f(dinv[d]*(hs[d] + sum_{s->d} hs[s]) + b) ----------------

template <int OUTC, bool SIG>
__global__ void aggregate_kernel(const int* __restrict__ rowptr, const int* __restrict__ csr_src,
                                 const float* __restrict__ hs, const float* __restrict__ dinv,
                                 const float* __restrict__ bias, float* __restrict__ out, int n) {
    constexpr int TPR = OUTC / 4;       // threads per node
    constexpr int NPB = 256 / TPR;      // nodes per block
    const int tid  = threadIdx.x;
    const int node = blockIdx.x * NPB + tid / TPR;
    const int p    = tid % TPR;
    if (node >= n) return;

    float4 acc = *(const float4*)&hs[node * OUTC + p * 4];  // self-loop term
    const int e0 = rowptr[node];
    const int e1 = rowptr[node + 1];
    for (int e = e0; e < e1; ++e) {
        int s = csr_src[e];
        float4 v = *(const float4*)&hs[s * OUTC + p * 4];
        acc.x += v.x; acc.y += v.y; acc.z += v.z; acc.w += v.w;
    }
    float sc = dinv[node];
    float4 bb = *(const float4*)&bias[p * 4];
    acc.x = acc.x * sc + bb.x;
    acc.y = acc.y * sc + bb.y;
    acc.z = acc.z * sc + bb.z;
    acc.w = acc.w * sc + bb.w;
    if (SIG) {
        acc.x = 1.0f / (1.0f + expf(-acc.x));
        acc.y = 1.0f / (1.0f + expf(-acc.y));
        acc.z = 1.0f / (1.0f + expf(-acc.z));
        acc.w = 1.0f / (1.0f + expf(-acc.w));
    }
    *(float4*)&out[node * OUTC + p * 4] = acc;
}

static inline size_t align256(size_t x) { return (x + 255) & ~size_t(255); }

extern "C" void kernel_launch(void* const* d_in, const int* in_sizes, int n_in,
                              void* d_out, int out_size, void* d_ws, size_t ws_size,
                              hipStream_t stream) {
    const float* x   = (const float*)d_in[0];
    const int*   e32 = (const int*)d_in[1];   // [2,E] int32
    const float* W0  = (const float*)d_in[2];
    const float* b0  = (const float*)d_in[3];
    const float* W1  = (const float*)d_in[4];
    const float* b1  = (const float*)d_in[5];
    float* out = (float*)d_out;

    const int N = in_sizes[0] / 128;   // 50000
    const int E = in_sizes[1] / 2;     // 800000
    const int* src = e32;
    const int* dst = e32 + E;

    // Workspace layout
    char* p = (char*)d_ws;
    int*   deg     = (int*)p;   p += align256((size_t)N * 4);
    float* dinv    = (float*)p; p += align256((size_t)N * 4);
    int*   rowptr  = (int*)p;   p += align256((size_t)(N + 1) * 4);
    int*   cursor  = (int*)p;   p += align256((size_t)N * 4);
    int*   bsum    = (int*)p;   p += align256((size_t)256 * 4);
    int*   csr_src = (int*)p;   p += align256((size_t)E * 4);
    float* hs1     = (float*)p; p += align256((size_t)N * 128 * 4);  // also reused as hs2 (64 cols)
    float* act     = (float*)p; p += align256((size_t)N * 128 * 4);
    float* hs2     = hs1;

    const int nb = (N + 1023) / 1024;   // scan blocks (49 <= 256)

    // ---- CSR build (shared by both layers) ----
    hipMemsetAsync(deg, 0, (size_t)N * 4, stream);
    deg_count_kernel<<<(E + BLK - 1) / BLK, BLK, 0, stream>>>(dst, deg, E);
    dinv_kernel<<<(N + BLK - 1) / BLK, BLK, 0, stream>>>(deg, dinv, N);
    scan1_kernel<<<nb, BLK, 0, stream>>>(deg, rowptr, bsum, N);
    scan2_kernel<<<1, BLK, 0, stream>>>(bsum, nb);
    scan3_kernel<<<(N + BLK - 1) / BLK, BLK, 0, stream>>>(rowptr, bsum, N, E);
    cursor_init_kernel<<<(N + BLK - 1) / BLK, BLK, 0, stream>>>(rowptr, cursor, N);
    fill_csr_kernel<<<(E + BLK - 1) / BLK, BLK, 0, stream>>>(src, dst, cursor, csr_src, E);

    // ---- Layer 1: 128 -> 128, sigmoid ----
    gemm_scale_kernel<128><<<(N + 7) / 8, BLK, 0, stream>>>(x, W0, dinv, hs1, N);
    aggregate_kernel<128, true><<<(N + 7) / 8, BLK, 0, stream>>>(rowptr, csr_src, hs1, dinv, b0, act, N);

    // ---- Layer 2: 128 -> 64, no activation ----
    gemm_scale_kernel<64><<<(N + 15) / 16, BLK, 0, stream>>>(act, W1, dinv, hs2, N);
    aggregate_kernel<64, false><<<(N + 15) / 16, BLK, 0, stream>>>(rowptr, csr_src, hs2, dinv, b1, out, N);
}

// Round 3
// 236.980 us; speedup vs baseline: 9.1159x; 1.1570x over previous
//
#include <hip/hip_runtime.h>
#include <math.h>

#define BLK 256

// ---------------- degree / CSR build ----------------

__global__ void deg_count_kernel(const int* __restrict__ dst, int* __restrict__ deg, int E) {
    int i = blockIdx.x * blockDim.x + threadIdx.x;
    if (i < E) atomicAdd(&deg[dst[i]], 1);
}

__global__ void dinv_kernel(const int* __restrict__ deg, float* __restrict__ dinv, int n) {
    int i = blockIdx.x * blockDim.x + threadIdx.x;
    if (i < n) dinv[i] = rsqrtf((float)(deg[i] + 1));  // +1 self-loop
}

// Exclusive scan of deg into rowptr: 1024 elements per block (256 thr x 4).
__global__ void scan1_kernel(const int* __restrict__ deg, int* __restrict__ rowptr,
                             int* __restrict__ bsum, int n) {
    __shared__ int s[BLK];
    int tid = threadIdx.x;
    int base = blockIdx.x * 1024 + tid * 4;
    int v[4];
    int sum = 0;
    #pragma unroll
    for (int j = 0; j < 4; ++j) {
        v[j] = (base + j < n) ? deg[base + j] : 0;
        sum += v[j];
    }
    s[tid] = sum;
    __syncthreads();
    #pragma unroll
    for (int off = 1; off < BLK; off <<= 1) {
        int t = 0;
        if (tid >= off) t = s[tid - off];
        __syncthreads();
        if (tid >= off) s[tid] += t;
        __syncthreads();
    }
    int run = s[tid] - sum;
    #pragma unroll
    for (int j = 0; j < 4; ++j) {
        if (base + j < n) rowptr[base + j] = run;
        run += v[j];
    }
    if (tid == BLK - 1) bsum[blockIdx.x] = s[BLK - 1];
}

__global__ void scan2_kernel(int* __restrict__ bsum, int nb) {
    __shared__ int s[BLK];
    int tid = threadIdx.x;
    int v = (tid < nb) ? bsum[tid] : 0;
    s[tid] = v;
    __syncthreads();
    #pragma unroll
    for (int off = 1; off < BLK; off <<= 1) {
        int t = 0;
        if (tid >= off) t = s[tid - off];
        __syncthreads();
        if (tid >= off) s[tid] += t;
        __syncthreads();
    }
    if (tid < nb) bsum[tid] = s[tid] - v;
}

__global__ void scan3_kernel(int* __restrict__ rowptr, const int* __restrict__ bsum,
                             int n, int E) {
    int i = blockIdx.x * blockDim.x + threadIdx.x;
    if (i < n) rowptr[i] += bsum[i >> 10];
    if (i == 0) rowptr[n] = E;
}

__global__ void cursor_init_kernel(const int* __restrict__ rowptr, int* __restrict__ cursor, int n) {
    int i = blockIdx.x * blockDim.x + threadIdx.x;
    if (i < n) cursor[i] = rowptr[i];
}

__global__ void fill_csr_kernel(const int* __restrict__ src, const int* __restrict__ dst,
                                int* __restrict__ cursor, int* __restrict__ csr_src, int E) {
    int e = blockIdx.x * blockDim.x + threadIdx.x;
    if (e < E) {
        int d = dst[e];
        int pos = atomicAdd(&cursor[d], 1);
        csr_src[pos] = src[e];
    }
}

// ---------------- GEMM: hs = (x @ W) * dinv[row] ----------------
// BM=32 rows/block, BN=OUTC cols. Thread (ct, rt): ct = tid%CT owns 4 cols,
// rt = tid/CT owns RPT rows. 16 (or 8) FMAs per 32 (24) B of LDS reads.

template <int OUTC>
__global__ void gemm_scale_kernel(const float* __restrict__ x, const float* __restrict__ W,
                                  const float* __restrict__ dinv,
                                  float* __restrict__ hs, int n) {
    constexpr int BM  = 32;
    constexpr int CT  = OUTC / 4;     // col-threads: 32 (128) or 16 (64)
    constexpr int RT  = 256 / CT;     // row-threads: 8 or 16
    constexpr int RPT = BM / RT;      // rows/thread: 4 or 2
    constexpr int KT  = 32;
    constexpr int XP  = KT + 4;       // pad keeps 16B alignment, spreads banks

    __shared__ float Ws[KT][OUTC];
    __shared__ float xs[BM][XP];

    const int tid  = threadIdx.x;
    const int ct   = tid % CT;
    const int rt   = tid / CT;
    const int row0 = blockIdx.x * BM;

    float4 acc[RPT];
    #pragma unroll
    for (int i = 0; i < RPT; ++i) acc[i] = make_float4(0.f, 0.f, 0.f, 0.f);

    for (int kt = 0; kt < 128; kt += KT) {
        // stage W tile: KT*OUTC floats
        constexpr int WLOAD = (KT * OUTC) / (256 * 4);
        #pragma unroll
        for (int l = 0; l < WLOAD; ++l) {
            int idx = (tid + l * 256) * 4;
            int kk  = idx / OUTC;
            int cc  = idx % OUTC;
            *(float4*)&Ws[kk][cc] = *(const float4*)&W[(kt + kk) * OUTC + cc];
        }
        // stage x tile: BM*KT floats, one float4 per thread
        {
            int idx = tid * 4;            // 256*4 = 1024 = BM*KT
            int rr  = idx / KT;
            int kk  = idx % KT;
            int grow = row0 + rr;
            float4 xv = (grow < n) ? *(const float4*)&x[(size_t)grow * 128 + kt + kk]
                                   : make_float4(0.f, 0.f, 0.f, 0.f);
            *(float4*)&xs[rr][kk] = xv;
        }
        __syncthreads();
        #pragma unroll
        for (int k = 0; k < KT; ++k) {
            float4 w = *(const float4*)&Ws[k][ct * 4];
            #pragma unroll
            for (int i = 0; i < RPT; ++i) {
                float xv = xs[rt * RPT + i][k];
                acc[i].x += xv * w.x; acc[i].y += xv * w.y;
                acc[i].z += xv * w.z; acc[i].w += xv * w.w;
            }
        }
        __syncthreads();
    }

    #pragma unroll
    for (int i = 0; i < RPT; ++i) {
        int row = row0 + rt * RPT + i;
        if (row < n) {
            float s = dinv[row];
            float4 v = make_float4(acc[i].x * s, acc[i].y * s, acc[i].z * s, acc[i].w * s);
            *(float4*)&hs[(size_t)row * OUTC + ct * 4] = v;
        }
    }
}

// ---------------- aggregate: out[d] = f(dinv[d]*(hs[d] + sum_{s->d} hs[s]) + b) ----------------

template <int OUTC, bool SIG>
__global__ void aggregate_kernel(const int* __restrict__ rowptr, const int* __restrict__ csr_src,
                                 const float* __restrict__ hs, const float* __restrict__ dinv,
                                 const float* __restrict__ bias, float* __restrict__ out, int n) {
    constexpr int TPR = OUTC / 4;       // threads per node
    constexpr int NPB = 256 / TPR;      // nodes per block
    const int tid  = threadIdx.x;
    const int node = blockIdx.x * NPB + tid / TPR;
    const int p    = tid % TPR;
    if (node >= n) return;

    const float* __restrict__ hp = hs + (size_t)p * 4;   // column offset
    float4 acc = *(const float4*)&hp[(size_t)node * OUTC];  // self-loop term
    int e       = rowptr[node];
    const int e1 = rowptr[node + 1];

    // 4-way unroll: 4 independent gathers in flight per thread
    for (; e + 4 <= e1; e += 4) {
        int s0 = csr_src[e + 0];
        int s1 = csr_src[e + 1];
        int s2 = csr_src[e + 2];
        int s3 = csr_src[e + 3];
        float4 v0 = *(const float4*)&hp[(size_t)s0 * OUTC];
        float4 v1 = *(const float4*)&hp[(size_t)s1 * OUTC];
        float4 v2 = *(const float4*)&hp[(size_t)s2 * OUTC];
        float4 v3 = *(const float4*)&hp[(size_t)s3 * OUTC];
        acc.x += (v0.x + v1.x) + (v2.x + v3.x);
        acc.y += (v0.y + v1.y) + (v2.y + v3.y);
        acc.z += (v0.z + v1.z) + (v2.z + v3.z);
        acc.w += (v0.w + v1.w) + (v2.w + v3.w);
    }
    for (; e < e1; ++e) {
        int s = csr_src[e];
        float4 v = *(const float4*)&hp[(size_t)s * OUTC];
        acc.x += v.x; acc.y += v.y; acc.z += v.z; acc.w += v.w;
    }

    float sc = dinv[node];
    float4 bb = *(const float4*)&bias[p * 4];
    acc.x = acc.x * sc + bb.x;
    acc.y = acc.y * sc + bb.y;
    acc.z = acc.z * sc + bb.z;
    acc.w = acc.w * sc + bb.w;
    if (SIG) {
        acc.x = 1.0f / (1.0f + expf(-acc.x));
        acc.y = 1.0f / (1.0f + expf(-acc.y));
        acc.z = 1.0f / (1.0f + expf(-acc.z));
        acc.w = 1.0f / (1.0f + expf(-acc.w));
    }
    *(float4*)&out[(size_t)node * OUTC + p * 4] = acc;
}

static inline size_t align256(size_t x) { return (x + 255) & ~size_t(255); }

extern "C" void kernel_launch(void* const* d_in, const int* in_sizes, int n_in,
                              void* d_out, int out_size, void* d_ws, size_t ws_size,
                              hipStream_t stream) {
    const float* x   = (const float*)d_in[0];
    const int*   e32 = (const int*)d_in[1];   // [2,E] int32
    const float* W0  = (const float*)d_in[2];
    const float* b0  = (const float*)d_in[3];
    const float* W1  = (const float*)d_in[4];
    const float* b1  = (const float*)d_in[5];
    float* out = (float*)d_out;

    const int N = in_sizes[0] / 128;   // 50000
    const int E = in_sizes[1] / 2;     // 800000
    const int* src = e32;
    const int* dst = e32 + E;

    // Workspace layout
    char* p = (char*)d_ws;
    int*   deg     = (int*)p;   p += align256((size_t)N * 4);
    float* dinv    = (float*)p; p += align256((size_t)N * 4);
    int*   rowptr  = (int*)p;   p += align256((size_t)(N + 1) * 4);
    int*   cursor  = (int*)p;   p += align256((size_t)N * 4);
    int*   bsum    = (int*)p;   p += align256((size_t)256 * 4);
    int*   csr_src = (int*)p;   p += align256((size_t)E * 4);
    float* hs1     = (float*)p; p += align256((size_t)N * 128 * 4);  // reused as hs2
    float* act     = (float*)p; p += align256((size_t)N * 128 * 4);
    float* hs2     = hs1;

    const int nb = (N + 1023) / 1024;

    // ---- CSR build (shared by both layers) ----
    hipMemsetAsync(deg, 0, (size_t)N * 4, stream);
    deg_count_kernel<<<(E + BLK - 1) / BLK, BLK, 0, stream>>>(dst, deg, E);
    dinv_kernel<<<(N + BLK - 1) / BLK, BLK, 0, stream>>>(deg, dinv, N);
    scan1_kernel<<<nb, BLK, 0, stream>>>(deg, rowptr, bsum, N);
    scan2_kernel<<<1, BLK, 0, stream>>>(bsum, nb);
    scan3_kernel<<<(N + BLK - 1) / BLK, BLK, 0, stream>>>(rowptr, bsum, N, E);
    cursor_init_kernel<<<(N + BLK - 1) / BLK, BLK, 0, stream>>>(rowptr, cursor, N);
    fill_csr_kernel<<<(E + BLK - 1) / BLK, BLK, 0, stream>>>(src, dst, cursor, csr_src, E);

    // ---- Layer 1: 128 -> 128, sigmoid ----
    gemm_scale_kernel<128><<<(N + 31) / 32, BLK, 0, stream>>>(x, W0, dinv, hs1, N);
    aggregate_kernel<128, true><<<(N + 7) / 8, BLK, 0, stream>>>(rowptr, csr_src, hs1, dinv, b0, act, N);

    // ---- Layer 2: 128 -> 64, no activation ----
    gemm_scale_kernel<64><<<(N + 31) / 32, BLK, 0, stream>>>(act, W1, dinv, hs2, N);
    aggregate_kernel<64, false><<<(N + 15) / 16, BLK, 0, stream>>>(rowptr, csr_src, hs2, dinv, b1, out, N);
}

// Round 4
// 198.924 us; speedup vs baseline: 10.8598x; 1.1913x over previous
//
#include <hip/hip_runtime.h>
#include <hip/hip_fp16.h>
#include <math.h>

#define BLK 256

// ---------------- degree / CSR build ----------------

__global__ void deg_count_kernel(const int* __restrict__ dst, int* __restrict__ deg, int E) {
    int i = blockIdx.x * blockDim.x + threadIdx.x;
    if (i < E) atomicAdd(&deg[dst[i]], 1);
}

// Exclusive scan of deg into rowptr (1024 elems/block) + dinv = rsqrt(deg+1).
__global__ void scan1_kernel(const int* __restrict__ deg, int* __restrict__ rowptr,
                             int* __restrict__ bsum, float* __restrict__ dinv, int n) {
    __shared__ int s[BLK];
    int tid = threadIdx.x;
    int base = blockIdx.x * 1024 + tid * 4;
    int v[4];
    int sum = 0;
    #pragma unroll
    for (int j = 0; j < 4; ++j) {
        v[j] = (base + j < n) ? deg[base + j] : 0;
        sum += v[j];
    }
    #pragma unroll
    for (int j = 0; j < 4; ++j)
        if (base + j < n) dinv[base + j] = rsqrtf((float)(v[j] + 1));
    s[tid] = sum;
    __syncthreads();
    #pragma unroll
    for (int off = 1; off < BLK; off <<= 1) {
        int t = 0;
        if (tid >= off) t = s[tid - off];
        __syncthreads();
        if (tid >= off) s[tid] += t;
        __syncthreads();
    }
    int run = s[tid] - sum;
    #pragma unroll
    for (int j = 0; j < 4; ++j) {
        if (base + j < n) rowptr[base + j] = run;
        run += v[j];
    }
    if (tid == BLK - 1) bsum[blockIdx.x] = s[BLK - 1];
}

__global__ void scan2_kernel(int* __restrict__ bsum, int nb) {
    __shared__ int s[BLK];
    int tid = threadIdx.x;
    int v = (tid < nb) ? bsum[tid] : 0;
    s[tid] = v;
    __syncthreads();
    #pragma unroll
    for (int off = 1; off < BLK; off <<= 1) {
        int t = 0;
        if (tid >= off) t = s[tid - off];
        __syncthreads();
        if (tid >= off) s[tid] += t;
        __syncthreads();
    }
    if (tid < nb) bsum[tid] = s[tid] - v;
}

// Add block offsets; also init cursor and rowptr[n].
__global__ void scan3_kernel(int* __restrict__ rowptr, const int* __restrict__ bsum,
                             int* __restrict__ cursor, int n, int E) {
    int i = blockIdx.x * blockDim.x + threadIdx.x;
    if (i < n) {
        int r = rowptr[i] + bsum[i >> 10];
        rowptr[i] = r;
        cursor[i] = r;
    }
    if (i == 0) rowptr[n] = E;
}

__global__ void fill_csr_kernel(const int* __restrict__ src, const int* __restrict__ dst,
                                int* __restrict__ cursor, int* __restrict__ csr_src, int E) {
    int e = blockIdx.x * blockDim.x + threadIdx.x;
    if (e < E) {
        int d = dst[e];
        int pos = atomicAdd(&cursor[d], 1);
        csr_src[pos] = src[e];
    }
}

// ---------------- GEMM: hs = fp16((x @ W) * dinv[row]) ----------------

template <int OUTC>
__global__ void gemm_scale_kernel(const float* __restrict__ x, const float* __restrict__ W,
                                  const float* __restrict__ dinv,
                                  __half* __restrict__ hs, int n) {
    constexpr int BM  = 32;
    constexpr int CT  = OUTC / 4;
    constexpr int RT  = 256 / CT;
    constexpr int RPT = BM / RT;
    constexpr int KT  = 32;
    constexpr int XP  = KT + 4;

    __shared__ float Ws[KT][OUTC];
    __shared__ float xs[BM][XP];

    const int tid  = threadIdx.x;
    const int ct   = tid % CT;
    const int rt   = tid / CT;
    const int row0 = blockIdx.x * BM;

    float4 acc[RPT];
    #pragma unroll
    for (int i = 0; i < RPT; ++i) acc[i] = make_float4(0.f, 0.f, 0.f, 0.f);

    for (int kt = 0; kt < 128; kt += KT) {
        constexpr int WLOAD = (KT * OUTC) / (256 * 4);
        #pragma unroll
        for (int l = 0; l < WLOAD; ++l) {
            int idx = (tid + l * 256) * 4;
            int kk  = idx / OUTC;
            int cc  = idx % OUTC;
            *(float4*)&Ws[kk][cc] = *(const float4*)&W[(kt + kk) * OUTC + cc];
        }
        {
            int idx = tid * 4;            // 256*4 = 1024 = BM*KT
            int rr  = idx / KT;
            int kk  = idx % KT;
            int grow = row0 + rr;
            float4 xv = (grow < n) ? *(const float4*)&x[(size_t)grow * 128 + kt + kk]
                                   : make_float4(0.f, 0.f, 0.f, 0.f);
            *(float4*)&xs[rr][kk] = xv;
        }
        __syncthreads();
        #pragma unroll
        for (int k = 0; k < KT; ++k) {
            float4 w = *(const float4*)&Ws[k][ct * 4];
            #pragma unroll
            for (int i = 0; i < RPT; ++i) {
                float xv = xs[rt * RPT + i][k];
                acc[i].x += xv * w.x; acc[i].y += xv * w.y;
                acc[i].z += xv * w.z; acc[i].w += xv * w.w;
            }
        }
        __syncthreads();
    }

    #pragma unroll
    for (int i = 0; i < RPT; ++i) {
        int row = row0 + rt * RPT + i;
        if (row < n) {
            float s = dinv[row];
            union { __half2 h2[2]; float2 f2; } u;
            u.h2[0] = __floats2half2_rn(acc[i].x * s, acc[i].y * s);
            u.h2[1] = __floats2half2_rn(acc[i].z * s, acc[i].w * s);
            *(float2*)&hs[(size_t)row * OUTC + ct * 4] = u.f2;
        }
    }
}

// ---------------- aggregate: out[d] = f(dinv[d]*(hs[d] + sum_{s->d} hs[s]) + b) ----------------
// 8 fp16 cols per thread (16B gathers), fp32 accumulation.

template <int OUTC, bool SIG>
__global__ void aggregate_kernel(const int* __restrict__ rowptr, const int* __restrict__ csr_src,
                                 const __half* __restrict__ hs, const float* __restrict__ dinv,
                                 const float* __restrict__ bias, float* __restrict__ out, int n) {
    constexpr int CPT = 8;              // fp16 cols per thread (16 B)
    constexpr int TPR = OUTC / CPT;     // 16 or 8 threads per node
    constexpr int NPB = 256 / TPR;
    const int tid  = threadIdx.x;
    const int node = blockIdx.x * NPB + tid / TPR;
    const int p    = tid % TPR;
    if (node >= n) return;

    const __half* __restrict__ hp = hs + (size_t)p * CPT;

    float acc[CPT];
    {
        float4 raw = *(const float4*)&hp[(size_t)node * OUTC];
        const __half2* h2 = (const __half2*)&raw;
        #pragma unroll
        for (int j = 0; j < 4; ++j) {
            float2 f = __half22float2(h2[j]);
            acc[2 * j] = f.x; acc[2 * j + 1] = f.y;
        }
    }

    int e        = rowptr[node];
    const int e1 = rowptr[node + 1];

    for (; e + 4 <= e1; e += 4) {
        int s0 = csr_src[e + 0];
        int s1 = csr_src[e + 1];
        int s2 = csr_src[e + 2];
        int s3 = csr_src[e + 3];
        float4 r0 = *(const float4*)&hp[(size_t)s0 * OUTC];
        float4 r1 = *(const float4*)&hp[(size_t)s1 * OUTC];
        float4 r2 = *(const float4*)&hp[(size_t)s2 * OUTC];
        float4 r3 = *(const float4*)&hp[(size_t)s3 * OUTC];
        const __half2* a0 = (const __half2*)&r0;
        const __half2* a1 = (const __half2*)&r1;
        const __half2* a2 = (const __half2*)&r2;
        const __half2* a3 = (const __half2*)&r3;
        #pragma unroll
        for (int j = 0; j < 4; ++j) {
            float2 f0 = __half22float2(a0[j]);
            float2 f1 = __half22float2(a1[j]);
            float2 f2 = __half22float2(a2[j]);
            float2 f3 = __half22float2(a3[j]);
            acc[2 * j]     += (f0.x + f1.x) + (f2.x + f3.x);
            acc[2 * j + 1] += (f0.y + f1.y) + (f2.y + f3.y);
        }
    }
    for (; e < e1; ++e) {
        int s = csr_src[e];
        float4 r = *(const float4*)&hp[(size_t)s * OUTC];
        const __half2* a = (const __half2*)&r;
        #pragma unroll
        for (int j = 0; j < 4; ++j) {
            float2 f = __half22float2(a[j]);
            acc[2 * j] += f.x; acc[2 * j + 1] += f.y;
        }
    }

    const float sc = dinv[node];
    float* o = &out[(size_t)node * OUTC + p * CPT];
    #pragma unroll
    for (int j = 0; j < CPT; ++j) {
        float v = acc[j] * sc + bias[p * CPT + j];
        if (SIG) v = 1.0f / (1.0f + expf(-v));
        acc[j] = v;
    }
    *(float4*)&o[0] = make_float4(acc[0], acc[1], acc[2], acc[3]);
    *(float4*)&o[4] = make_float4(acc[4], acc[5], acc[6], acc[7]);
}

static inline size_t align256(size_t x) { return (x + 255) & ~size_t(255); }

extern "C" void kernel_launch(void* const* d_in, const int* in_sizes, int n_in,
                              void* d_out, int out_size, void* d_ws, size_t ws_size,
                              hipStream_t stream) {
    const float* x   = (const float*)d_in[0];
    const int*   e32 = (const int*)d_in[1];   // [2,E] int32
    const float* W0  = (const float*)d_in[2];
    const float* b0  = (const float*)d_in[3];
    const float* W1  = (const float*)d_in[4];
    const float* b1  = (const float*)d_in[5];
    float* out = (float*)d_out;

    const int N = in_sizes[0] / 128;   // 50000
    const int E = in_sizes[1] / 2;     // 800000
    const int* src = e32;
    const int* dst = e32 + E;

    // Workspace layout
    char* p = (char*)d_ws;
    int*    deg     = (int*)p;    p += align256((size_t)N * 4);
    float*  dinv    = (float*)p;  p += align256((size_t)N * 4);
    int*    rowptr  = (int*)p;    p += align256((size_t)(N + 1) * 4);
    int*    cursor  = (int*)p;    p += align256((size_t)N * 4);
    int*    bsum    = (int*)p;    p += align256((size_t)256 * 4);
    int*    csr_src = (int*)p;    p += align256((size_t)E * 4);
    __half* hs      = (__half*)p; p += align256((size_t)N * 128 * 2);  // fp16, reused by layer 2
    float*  act     = (float*)p;  p += align256((size_t)N * 128 * 4);

    const int nb = (N + 1023) / 1024;

    // ---- CSR build (shared by both layers) ----
    hipMemsetAsync(deg, 0, (size_t)N * 4, stream);
    deg_count_kernel<<<(E + BLK - 1) / BLK, BLK, 0, stream>>>(dst, deg, E);
    scan1_kernel<<<nb, BLK, 0, stream>>>(deg, rowptr, bsum, dinv, N);
    scan2_kernel<<<1, BLK, 0, stream>>>(bsum, nb);
    scan3_kernel<<<(N + BLK - 1) / BLK, BLK, 0, stream>>>(rowptr, bsum, cursor, N, E);
    fill_csr_kernel<<<(E + BLK - 1) / BLK, BLK, 0, stream>>>(src, dst, cursor, csr_src, E);

    // ---- Layer 1: 128 -> 128, sigmoid ----
    gemm_scale_kernel<128><<<(N + 31) / 32, BLK, 0, stream>>>(x, W0, dinv, hs, N);
    aggregate_kernel<128, true><<<(N + 15) / 16, BLK, 0, stream>>>(rowptr, csr_src, hs, dinv, b0, act, N);

    // ---- Layer 2: 128 -> 64, no activation ----
    gemm_scale_kernel<64><<<(N + 31) / 32, BLK, 0, stream>>>(act, W1, dinv, hs, N);
    aggregate_kernel<64, false><<<(N + 31) / 32, BLK, 0, stream>>>(rowptr, csr_src, hs, dinv, b1, out, N);
}

// Round 5
// 161.647 us; speedup vs baseline: 13.3641x; 1.2306x over previous
//
#include <hip/hip_runtime.h>
#include <hip/hip_fp16.h>
#include <math.h>

#define BLK 256

// ---------------- degree / CSR build ----------------

// rank[e] = arrival order of edge e at its dst; deg[d] = in-degree (excl self-loop).
__global__ void deg_rank_kernel(const int* __restrict__ dst, int* __restrict__ deg,
                                int* __restrict__ rank, int E) {
    int e = blockIdx.x * blockDim.x + threadIdx.x;
    if (e < E) rank[e] = atomicAdd(&deg[dst[e]], 1);
}

// Exclusive scan of deg into rowptr (1024 elems/block) + dinv = rsqrt(deg+1).
__global__ void scan1_kernel(const int* __restrict__ deg, int* __restrict__ rowptr,
                             int* __restrict__ bsum, float* __restrict__ dinv, int n) {
    __shared__ int s[BLK];
    int tid = threadIdx.x;
    int base = blockIdx.x * 1024 + tid * 4;
    int v[4];
    int sum = 0;
    #pragma unroll
    for (int j = 0; j < 4; ++j) {
        v[j] = (base + j < n) ? deg[base + j] : 0;
        sum += v[j];
    }
    #pragma unroll
    for (int j = 0; j < 4; ++j)
        if (base + j < n) dinv[base + j] = rsqrtf((float)(v[j] + 1));
    s[tid] = sum;
    __syncthreads();
    #pragma unroll
    for (int off = 1; off < BLK; off <<= 1) {
        int t = 0;
        if (tid >= off) t = s[tid - off];
        __syncthreads();
        if (tid >= off) s[tid] += t;
        __syncthreads();
    }
    int run = s[tid] - sum;
    #pragma unroll
    for (int j = 0; j < 4; ++j) {
        if (base + j < n) rowptr[base + j] = run;
        run += v[j];
    }
    if (tid == BLK - 1) bsum[blockIdx.x] = s[BLK - 1];
}

__global__ void scan2_kernel(int* __restrict__ bsum, int nb) {
    __shared__ int s[BLK];
    int tid = threadIdx.x;
    int v = (tid < nb) ? bsum[tid] : 0;
    s[tid] = v;
    __syncthreads();
    #pragma unroll
    for (int off = 1; off < BLK; off <<= 1) {
        int t = 0;
        if (tid >= off) t = s[tid - off];
        __syncthreads();
        if (tid >= off) s[tid] += t;
        __syncthreads();
    }
    if (tid < nb) bsum[tid] = s[tid] - v;
}

__global__ void scan3_kernel(int* __restrict__ rowptr, const int* __restrict__ bsum,
                             int n, int E) {
    int i = blockIdx.x * blockDim.x + threadIdx.x;
    if (i < n) rowptr[i] += bsum[i >> 10];
    if (i == 0) rowptr[n] = E;
}

// Atomic-free fill: pos = rowptr[dst] + rank.
__global__ void fill_pos_kernel(const int* __restrict__ src, const int* __restrict__ dst,
                                const int* __restrict__ rank, const int* __restrict__ rowptr,
                                int* __restrict__ csr_src, int E) {
    int e = blockIdx.x * blockDim.x + threadIdx.x;
    if (e < E) {
        int pos = rowptr[dst[e]] + rank[e];
        csr_src[pos] = src[e];
    }
}

// ---------------- GEMM: hs = fp16((x @ W) * dinv[row]) ----------------

template <int OUTC>
__global__ void gemm_scale_kernel(const float* __restrict__ x, const float* __restrict__ W,
                                  const float* __restrict__ dinv,
                                  __half* __restrict__ hs, int n) {
    constexpr int BM  = 32;
    constexpr int CT  = OUTC / 4;
    constexpr int RT  = 256 / CT;
    constexpr int RPT = BM / RT;
    constexpr int KT  = 32;
    constexpr int XP  = KT + 4;

    __shared__ float Ws[KT][OUTC];
    __shared__ float xs[BM][XP];

    const int tid  = threadIdx.x;
    const int ct   = tid % CT;
    const int rt   = tid / CT;
    const int row0 = blockIdx.x * BM;

    float4 acc[RPT];
    #pragma unroll
    for (int i = 0; i < RPT; ++i) acc[i] = make_float4(0.f, 0.f, 0.f, 0.f);

    for (int kt = 0; kt < 128; kt += KT) {
        constexpr int WLOAD = (KT * OUTC) / (256 * 4);
        #pragma unroll
        for (int l = 0; l < WLOAD; ++l) {
            int idx = (tid + l * 256) * 4;
            int kk  = idx / OUTC;
            int cc  = idx % OUTC;
            *(float4*)&Ws[kk][cc] = *(const float4*)&W[(kt + kk) * OUTC + cc];
        }
        {
            int idx = tid * 4;            // 256*4 = 1024 = BM*KT
            int rr  = idx / KT;
            int kk  = idx % KT;
            int grow = row0 + rr;
            float4 xv = (grow < n) ? *(const float4*)&x[(size_t)grow * 128 + kt + kk]
                                   : make_float4(0.f, 0.f, 0.f, 0.f);
            *(float4*)&xs[rr][kk] = xv;
        }
        __syncthreads();
        #pragma unroll
        for (int k = 0; k < KT; ++k) {
            float4 w = *(const float4*)&Ws[k][ct * 4];
            #pragma unroll
            for (int i = 0; i < RPT; ++i) {
                float xv = xs[rt * RPT + i][k];
                acc[i].x += xv * w.x; acc[i].y += xv * w.y;
                acc[i].z += xv * w.z; acc[i].w += xv * w.w;
            }
        }
        __syncthreads();
    }

    #pragma unroll
    for (int i = 0; i < RPT; ++i) {
        int row = row0 + rt * RPT + i;
        if (row < n) {
            float s = dinv[row];
            union { __half2 h2[2]; float2 f2; } u;
            u.h2[0] = __floats2half2_rn(acc[i].x * s, acc[i].y * s);
            u.h2[1] = __floats2half2_rn(acc[i].z * s, acc[i].w * s);
            *(float2*)&hs[(size_t)row * OUTC + ct * 4] = u.f2;
        }
    }
}

// ---------------- aggregate: out[d] = f(dinv[d]*(hs[d] + sum_{s->d} hs[s]) + b) ----------------
// 8 fp16 cols per thread (16B gathers), fp32 accumulation, 8/4-way unrolled gather loop.

template <int OUTC, bool SIG>
__global__ void aggregate_kernel(const int* __restrict__ rowptr, const int* __restrict__ csr_src,
                                 const __half* __restrict__ hs, const float* __restrict__ dinv,
                                 const float* __restrict__ bias, float* __restrict__ out, int n) {
    constexpr int CPT = 8;              // fp16 cols per thread (16 B)
    constexpr int TPR = OUTC / CPT;     // 16 or 8 threads per node
    constexpr int NPB = 256 / TPR;
    const int tid  = threadIdx.x;
    const int node = blockIdx.x * NPB + tid / TPR;
    const int p    = tid % TPR;
    if (node >= n) return;

    const __half* __restrict__ hp = hs + (size_t)p * CPT;

    float acc[CPT];
    {
        float4 raw = *(const float4*)&hp[(size_t)node * OUTC];
        const __half2* h2 = (const __half2*)&raw;
        #pragma unroll
        for (int j = 0; j < 4; ++j) {
            float2 f = __half22float2(h2[j]);
            acc[2 * j] = f.x; acc[2 * j + 1] = f.y;
        }
    }

    int e        = rowptr[node];
    const int e1 = rowptr[node + 1];

    for (; e + 8 <= e1; e += 8) {
        int s[8];
        #pragma unroll
        for (int u = 0; u < 8; ++u) s[u] = csr_src[e + u];
        float4 r[8];
        #pragma unroll
        for (int u = 0; u < 8; ++u) r[u] = *(const float4*)&hp[(size_t)s[u] * OUTC];
        #pragma unroll
        for (int j = 0; j < 4; ++j) {
            #pragma unroll
            for (int u = 0; u < 8; ++u) {
                float2 f = __half22float2(((const __half2*)&r[u])[j]);
                acc[2 * j] += f.x; acc[2 * j + 1] += f.y;
            }
        }
    }
    for (; e + 4 <= e1; e += 4) {
        int s[4];
        #pragma unroll
        for (int u = 0; u < 4; ++u) s[u] = csr_src[e + u];
        float4 r[4];
        #pragma unroll
        for (int u = 0; u < 4; ++u) r[u] = *(const float4*)&hp[(size_t)s[u] * OUTC];
        #pragma unroll
        for (int j = 0; j < 4; ++j) {
            #pragma unroll
            for (int u = 0; u < 4; ++u) {
                float2 f = __half22float2(((const __half2*)&r[u])[j]);
                acc[2 * j] += f.x; acc[2 * j + 1] += f.y;
            }
        }
    }
    for (; e < e1; ++e) {
        int s = csr_src[e];
        float4 r = *(const float4*)&hp[(size_t)s * OUTC];
        const __half2* a = (const __half2*)&r;
        #pragma unroll
        for (int j = 0; j < 4; ++j) {
            float2 f = __half22float2(a[j]);
            acc[2 * j] += f.x; acc[2 * j + 1] += f.y;
        }
    }

    const float sc = dinv[node];
    float* o = &out[(size_t)node * OUTC + p * CPT];
    #pragma unroll
    for (int j = 0; j < CPT; ++j) {
        float v = acc[j] * sc + bias[p * CPT + j];
        if (SIG) v = 1.0f / (1.0f + expf(-v));
        acc[j] = v;
    }
    *(float4*)&o[0] = make_float4(acc[0], acc[1], acc[2], acc[3]);
    *(float4*)&o[4] = make_float4(acc[4], acc[5], acc[6], acc[7]);
}

static inline size_t align256(size_t x) { return (x + 255) & ~size_t(255); }

extern "C" void kernel_launch(void* const* d_in, const int* in_sizes, int n_in,
                              void* d_out, int out_size, void* d_ws, size_t ws_size,
                              hipStream_t stream) {
    const float* x   = (const float*)d_in[0];
    const int*   e32 = (const int*)d_in[1];   // [2,E] int32
    const float* W0  = (const float*)d_in[2];
    const float* b0  = (const float*)d_in[3];
    const float* W1  = (const float*)d_in[4];
    const float* b1  = (const float*)d_in[5];
    float* out = (float*)d_out;

    const int N = in_sizes[0] / 128;   // 50000
    const int E = in_sizes[1] / 2;     // 800000
    const int* src = e32;
    const int* dst = e32 + E;

    // Workspace layout
    char* p = (char*)d_ws;
    int*    deg     = (int*)p;    p += align256((size_t)N * 4);
    float*  dinv    = (float*)p;  p += align256((size_t)N * 4);
    int*    rowptr  = (int*)p;    p += align256((size_t)(N + 1) * 4);
    int*    rank    = (int*)p;    p += align256((size_t)E * 4);
    int*    bsum    = (int*)p;    p += align256((size_t)256 * 4);
    int*    csr_src = (int*)p;    p += align256((size_t)E * 4);
    __half* hs      = (__half*)p; p += align256((size_t)N * 128 * 2);  // fp16, reused by layer 2
    float*  act     = (float*)p;  p += align256((size_t)N * 128 * 4);

    const int nb = (N + 1023) / 1024;

    // ---- CSR build (shared by both layers) ----
    hipMemsetAsync(deg, 0, (size_t)N * 4, stream);
    deg_rank_kernel<<<(E + BLK - 1) / BLK, BLK, 0, stream>>>(dst, deg, rank, E);
    scan1_kernel<<<nb, BLK, 0, stream>>>(deg, rowptr, bsum, dinv, N);
    scan2_kernel<<<1, BLK, 0, stream>>>(bsum, nb);
    scan3_kernel<<<(N + BLK - 1) / BLK, BLK, 0, stream>>>(rowptr, bsum, N, E);
    fill_pos_kernel<<<(E + BLK - 1) / BLK, BLK, 0, stream>>>(src, dst, rank, rowptr, csr_src, E);

    // ---- Layer 1: 128 -> 128, sigmoid ----
    gemm_scale_kernel<128><<<(N + 31) / 32, BLK, 0, stream>>>(x, W0, dinv, hs, N);
    aggregate_kernel<128, true><<<(N + 15) / 16, BLK, 0, stream>>>(rowptr, csr_src, hs, dinv, b0, act, N);

    // ---- Layer 2: 128 -> 64, no activation ----
    gemm_scale_kernel<64><<<(N + 31) / 32, BLK, 0, stream>>>(act, W1, dinv, hs, N);
    aggregate_kernel<64, false><<<(N + 31) / 32, BLK, 0, stream>>>(rowptr, csr_src, hs, dinv, b1, out, N);
}

// Round 6
// 161.543 us; speedup vs baseline: 13.3728x; 1.0006x over previous
//
#include <hip/hip_runtime.h>
#include <hip/hip_fp16.h>
#include <math.h>

#define BLK 256

// ---------------- degree / CSR build ----------------

__global__ void zero_kernel(int4* __restrict__ p, int n4) {
    int i = blockIdx.x * blockDim.x + threadIdx.x;
    if (i < n4) p[i] = make_int4(0, 0, 0, 0);
}

// rank[e] = arrival order of edge e at its dst; deg[d] = in-degree (excl self-loop).
__global__ void deg_rank_kernel(const int* __restrict__ dst, int* __restrict__ deg,
                                int* __restrict__ rank, int E) {
    int e = blockIdx.x * blockDim.x + threadIdx.x;
    if (e < E) rank[e] = atomicAdd(&deg[dst[e]], 1);
}

// Exclusive scan of deg into rowptr (1024 elems/block) + dinv = rsqrt(deg+1).
__global__ void scan1_kernel(const int* __restrict__ deg, int* __restrict__ rowptr,
                             int* __restrict__ bsum, float* __restrict__ dinv, int n) {
    __shared__ int s[BLK];
    int tid = threadIdx.x;
    int base = blockIdx.x * 1024 + tid * 4;
    int v[4];
    int sum = 0;
    #pragma unroll
    for (int j = 0; j < 4; ++j) {
        v[j] = (base + j < n) ? deg[base + j] : 0;
        sum += v[j];
    }
    #pragma unroll
    for (int j = 0; j < 4; ++j)
        if (base + j < n) dinv[base + j] = rsqrtf((float)(v[j] + 1));
    s[tid] = sum;
    __syncthreads();
    #pragma unroll
    for (int off = 1; off < BLK; off <<= 1) {
        int t = 0;
        if (tid >= off) t = s[tid - off];
        __syncthreads();
        if (tid >= off) s[tid] += t;
        __syncthreads();
    }
    int run = s[tid] - sum;
    #pragma unroll
    for (int j = 0; j < 4; ++j) {
        if (base + j < n) rowptr[base + j] = run;
        run += v[j];
    }
    if (tid == BLK - 1) bsum[blockIdx.x] = s[BLK - 1];
}

__global__ void scan2_kernel(int* __restrict__ bsum, int nb) {
    __shared__ int s[BLK];
    int tid = threadIdx.x;
    int v = (tid < nb) ? bsum[tid] : 0;
    s[tid] = v;
    __syncthreads();
    #pragma unroll
    for (int off = 1; off < BLK; off <<= 1) {
        int t = 0;
        if (tid >= off) t = s[tid - off];
        __syncthreads();
        if (tid >= off) s[tid] += t;
        __syncthreads();
    }
    if (tid < nb) bsum[tid] = s[tid] - v;
}

__global__ void scan3_kernel(int* __restrict__ rowptr, const int* __restrict__ bsum,
                             int n, int E) {
    int i = blockIdx.x * blockDim.x + threadIdx.x;
    if (i < n) rowptr[i] += bsum[i >> 10];
    if (i == 0) rowptr[n] = E;
}

// Atomic-free fill: pos = rowptr[dst] + rank.
__global__ void fill_pos_kernel(const int* __restrict__ src, const int* __restrict__ dst,
                                const int* __restrict__ rank, const int* __restrict__ rowptr,
                                int* __restrict__ csr_src, int E) {
    int e = blockIdx.x * blockDim.x + threadIdx.x;
    if (e < E) {
        int pos = rowptr[dst[e]] + rank[e];
        csr_src[pos] = src[e];
    }
}

// ---------------- GEMM: hs = fp16((x @ W) * dinv[row]) ----------------

template <int OUTC>
__global__ void gemm_scale_kernel(const float* __restrict__ x, const float* __restrict__ W,
                                  const float* __restrict__ dinv,
                                  __half* __restrict__ hs, int n) {
    constexpr int BM  = 32;
    constexpr int CT  = OUTC / 4;
    constexpr int RT  = 256 / CT;
    constexpr int RPT = BM / RT;
    constexpr int KT  = 32;
    constexpr int XP  = KT + 4;

    __shared__ float Ws[KT][OUTC];
    __shared__ float xs[BM][XP];

    const int tid  = threadIdx.x;
    const int ct   = tid % CT;
    const int rt   = tid / CT;
    const int row0 = blockIdx.x * BM;

    float4 acc[RPT];
    #pragma unroll
    for (int i = 0; i < RPT; ++i) acc[i] = make_float4(0.f, 0.f, 0.f, 0.f);

    for (int kt = 0; kt < 128; kt += KT) {
        constexpr int WLOAD = (KT * OUTC) / (256 * 4);
        #pragma unroll
        for (int l = 0; l < WLOAD; ++l) {
            int idx = (tid + l * 256) * 4;
            int kk  = idx / OUTC;
            int cc  = idx % OUTC;
            *(float4*)&Ws[kk][cc] = *(const float4*)&W[(kt + kk) * OUTC + cc];
        }
        {
            int idx = tid * 4;            // 256*4 = 1024 = BM*KT
            int rr  = idx / KT;
            int kk  = idx % KT;
            int grow = row0 + rr;
            float4 xv = (grow < n) ? *(const float4*)&x[(size_t)grow * 128 + kt + kk]
                                   : make_float4(0.f, 0.f, 0.f, 0.f);
            *(float4*)&xs[rr][kk] = xv;
        }
        __syncthreads();
        #pragma unroll
        for (int k = 0; k < KT; ++k) {
            float4 w = *(const float4*)&Ws[k][ct * 4];
            #pragma unroll
            for (int i = 0; i < RPT; ++i) {
                float xv = xs[rt * RPT + i][k];
                acc[i].x += xv * w.x; acc[i].y += xv * w.y;
                acc[i].z += xv * w.z; acc[i].w += xv * w.w;
            }
        }
        __syncthreads();
    }

    #pragma unroll
    for (int i = 0; i < RPT; ++i) {
        int row = row0 + rt * RPT + i;
        if (row < n) {
            float s = dinv[row];
            union { __half2 h2[2]; float2 f2; } u;
            u.h2[0] = __floats2half2_rn(acc[i].x * s, acc[i].y * s);
            u.h2[1] = __floats2half2_rn(acc[i].z * s, acc[i].w * s);
            *(float2*)&hs[(size_t)row * OUTC + ct * 4] = u.f2;
        }
    }
}

// ---------------- aggregate: out[d] = f(dinv[d]*(hs[d] + sum_{s->d} hs[s]) + b) ----------------
// 8 fp16 cols per thread (16B gathers), fp32 accumulation, 8/4-way unrolled gather loop.

template <int OUTC, bool SIG>
__global__ void aggregate_kernel(const int* __restrict__ rowptr, const int* __restrict__ csr_src,
                                 const __half* __restrict__ hs, const float* __restrict__ dinv,
                                 const float* __restrict__ bias, float* __restrict__ out, int n) {
    constexpr int CPT = 8;              // fp16 cols per thread (16 B)
    constexpr int TPR = OUTC / CPT;     // 16 or 8 threads per node
    constexpr int NPB = 256 / TPR;
    const int tid  = threadIdx.x;
    const int node = blockIdx.x * NPB + tid / TPR;
    const int p    = tid % TPR;
    if (node >= n) return;

    const __half* __restrict__ hp = hs + (size_t)p * CPT;

    float acc[CPT];
    {
        float4 raw = *(const float4*)&hp[(size_t)node * OUTC];
        const __half2* h2 = (const __half2*)&raw;
        #pragma unroll
        for (int j = 0; j < 4; ++j) {
            float2 f = __half22float2(h2[j]);
            acc[2 * j] = f.x; acc[2 * j + 1] = f.y;
        }
    }

    int e        = rowptr[node];
    const int e1 = rowptr[node + 1];

    for (; e + 8 <= e1; e += 8) {
        int s[8];
        #pragma unroll
        for (int u = 0; u < 8; ++u) s[u] = csr_src[e + u];
        float4 r[8];
        #pragma unroll
        for (int u = 0; u < 8; ++u) r[u] = *(const float4*)&hp[(size_t)s[u] * OUTC];
        #pragma unroll
        for (int j = 0; j < 4; ++j) {
            #pragma unroll
            for (int u = 0; u < 8; ++u) {
                float2 f = __half22float2(((const __half2*)&r[u])[j]);
                acc[2 * j] += f.x; acc[2 * j + 1] += f.y;
            }
        }
    }
    for (; e + 4 <= e1; e += 4) {
        int s[4];
        #pragma unroll
        for (int u = 0; u < 4; ++u) s[u] = csr_src[e + u];
        float4 r[4];
        #pragma unroll
        for (int u = 0; u < 4; ++u) r[u] = *(const float4*)&hp[(size_t)s[u] * OUTC];
        #pragma unroll
        for (int j = 0; j < 4; ++j) {
            #pragma unroll
            for (int u = 0; u < 4; ++u) {
                float2 f = __half22float2(((const __half2*)&r[u])[j]);
                acc[2 * j] += f.x; acc[2 * j + 1] += f.y;
            }
        }
    }
    for (; e < e1; ++e) {
        int s = csr_src[e];
        float4 r = *(const float4*)&hp[(size_t)s * OUTC];
        const __half2* a = (const __half2*)&r;
        #pragma unroll
        for (int j = 0; j < 4; ++j) {
            float2 f = __half22float2(a[j]);
            acc[2 * j] += f.x; acc[2 * j + 1] += f.y;
        }
    }

    const float sc = dinv[node];
    float* o = &out[(size_t)node * OUTC + p * CPT];
    #pragma unroll
    for (int j = 0; j < CPT; ++j) {
        float v = acc[j] * sc + bias[p * CPT + j];
        if (SIG) v = 1.0f / (1.0f + expf(-v));
        acc[j] = v;
    }
    *(float4*)&o[0] = make_float4(acc[0], acc[1], acc[2], acc[3]);
    *(float4*)&o[4] = make_float4(acc[4], acc[5], acc[6], acc[7]);
}

static inline size_t align256(size_t x) { return (x + 255) & ~size_t(255); }

extern "C" void kernel_launch(void* const* d_in, const int* in_sizes, int n_in,
                              void* d_out, int out_size, void* d_ws, size_t ws_size,
                              hipStream_t stream) {
    const float* x   = (const float*)d_in[0];
    const int*   e32 = (const int*)d_in[1];   // [2,E] int32
    const float* W0  = (const float*)d_in[2];
    const float* b0  = (const float*)d_in[3];
    const float* W1  = (const float*)d_in[4];
    const float* b1  = (const float*)d_in[5];
    float* out = (float*)d_out;

    const int N = in_sizes[0] / 128;   // 50000
    const int E = in_sizes[1] / 2;     // 800000
    const int* src = e32;
    const int* dst = e32 + E;

    // Workspace layout (deg first, 16B-aligned for int4 zeroing)
    char* p = (char*)d_ws;
    int*    deg     = (int*)p;    p += align256((size_t)N * 4);
    float*  dinv    = (float*)p;  p += align256((size_t)N * 4);
    int*    rowptr  = (int*)p;    p += align256((size_t)(N + 1) * 4);
    int*    rank    = (int*)p;    p += align256((size_t)E * 4);
    int*    bsum    = (int*)p;    p += align256((size_t)256 * 4);
    int*    csr_src = (int*)p;    p += align256((size_t)E * 4);
    __half* hs      = (__half*)p; p += align256((size_t)N * 128 * 2);  // fp16, reused by layer 2
    float*  act     = (float*)p;  p += align256((size_t)N * 128 * 4);

    const int nb = (N + 1023) / 1024;
    const int n4 = (N + 3) / 4;        // deg allocation is 256B-aligned; int4-safe

    // ---- CSR build (shared by both layers) ----
    zero_kernel<<<(n4 + BLK - 1) / BLK, BLK, 0, stream>>>((int4*)deg, n4);
    deg_rank_kernel<<<(E + BLK - 1) / BLK, BLK, 0, stream>>>(dst, deg, rank, E);
    scan1_kernel<<<nb, BLK, 0, stream>>>(deg, rowptr, bsum, dinv, N);
    scan2_kernel<<<1, BLK, 0, stream>>>(bsum, nb);
    scan3_kernel<<<(N + BLK - 1) / BLK, BLK, 0, stream>>>(rowptr, bsum, N, E);
    fill_pos_kernel<<<(E + BLK - 1) / BLK, BLK, 0, stream>>>(src, dst, rank, rowptr, csr_src, E);

    // ---- Layer 1: 128 -> 128, sigmoid ----
    gemm_scale_kernel<128><<<(N + 31) / 32, BLK, 0, stream>>>(x, W0, dinv, hs, N);
    aggregate_kernel<128, true><<<(N + 15) / 16, BLK, 0, stream>>>(rowptr, csr_src, hs, dinv, b0, act, N);

    // ---- Layer 2: 128 -> 64, no activation ----
    gemm_scale_kernel<64><<<(N + 31) / 32, BLK, 0, stream>>>(act, W1, dinv, hs, N);
    aggregate_kernel<64, false><<<(N + 31) / 32, BLK, 0, stream>>>(rowptr, csr_src, hs, dinv, b1, out, N);
}